// Round 16
// baseline (118.045 us; speedup 1.0000x reference)
//
#include <hip/hip_runtime.h>
#include <hip/hip_fp8.h>
#include <stdint.h>

// ---------------------------------------------------------------------------
// AttentionBlock: GroupNorm(32) -> q,k,v 1x1 conv -> full attention (N=4096,
// C=512, single head) -> out proj + residual.
// R16: revert R15 bundle to R14 baseline; keep exp->exp2 fold; add XCD-aware
//      block swizzle to s_gemm (each XCD owns 8 n-panels -> K-panels L2-hot).
// Workspace:
//   hn/part0/ao bf16 [2][4096][512] @ 0
//   q/part1     bf16 [2][4096][512] @ 8 MB   (gnpart early, part1 late)
//   vtf8        fp8  [2][512][4096] @ 24 MB
//   wqt..wot    bf16 [n][k]         @ 32 MB
//   S           fp8  [2][4096][4096]@ 34 MB  (32 MiB, exp'd)
//   lpart f32 [2][64][4096] @ 68 MB
//   qf8 fp8 [2][4096][512] @ 72 MB ; kf8 @ 76 MB
// ---------------------------------------------------------------------------

typedef unsigned short u16;
typedef unsigned char u8;
typedef short s16x8 __attribute__((ext_vector_type(8)));   // 8 bf16 bits
typedef float f32x4 __attribute__((ext_vector_type(4)));
typedef int i32x8 __attribute__((ext_vector_type(8)));
typedef float f32x16 __attribute__((ext_vector_type(16)));

#define NTOK 4096
#define CH   512

__device__ inline u16 f2bf(float f) {
  union { float f; uint32_t u; } v; v.f = f;
  uint32_t r = v.u + 0x7FFFu + ((v.u >> 16) & 1u);   // RNE
  return (u16)(r >> 16);
}
__device__ inline float bf2f(u16 b) {
  union { uint32_t u; float f; } v; v.u = (uint32_t)b << 16; return v.f;
}
__device__ inline f32x4 mfma16(s16x8 a, s16x8 b, f32x4 c) {
  return __builtin_amdgcn_mfma_f32_16x16x32_bf16(a, b, c, 0, 0, 0);
}
// block-scaled fp8 MFMA, scales = 1.0 (E8M0 bias 127) -> plain fp8 GEMM at 2x rate
__device__ inline f32x16 mfma_mx8(i32x8 a, i32x8 b, f32x16 c) {
  return __builtin_amdgcn_mfma_scale_f32_32x32x64_f8f6f4(
      a, b, c, 0 /*cbsz=fp8*/, 0 /*blgp=fp8*/,
      0, 0x7F7F7F7F, 0, 0x7F7F7F7F);
}
// pack 4 floats -> 4 fp8 e4m3 bytes (saturating)
__device__ inline uint32_t pk_fp8x4(float e0, float e1, float e2, float e3) {
#if __has_builtin(__builtin_amdgcn_cvt_pk_fp8_f32)
  int v = __builtin_amdgcn_cvt_pk_fp8_f32(e0, e1, 0, false);
  v = __builtin_amdgcn_cvt_pk_fp8_f32(e2, e3, v, true);
  return (uint32_t)v;
#else
  __hip_fp8_e4m3 a(e0), b(e1), c(e2), d(e3);
  return (uint32_t)*(u8*)&a | ((uint32_t)*(u8*)&b << 8) |
         ((uint32_t)*(u8*)&c << 16) | ((uint32_t)*(u8*)&d << 24);
#endif
}
__device__ inline u8 f2fp8(float x) {
#if __has_builtin(__builtin_amdgcn_cvt_pk_fp8_f32)
  int v = __builtin_amdgcn_cvt_pk_fp8_f32(x, x, 0, false);
  return (u8)(v & 0xFF);
#else
  __hip_fp8_e4m3 h(x); return *(u8*)&h;
#endif
}
// global -> LDS direct 16B copy (dest = wave-uniform base + lane*16)
__device__ inline void gload_lds16(const void* g, void* l) {
  __builtin_amdgcn_global_load_lds(
      (const __attribute__((address_space(1))) unsigned*)g,
      (__attribute__((address_space(3))) unsigned*)l, 16, 0, 0);
}
__device__ inline uint4 addbf8(uint4 a, uint4 b) {
  union { uint4 v; u16 h[8]; } A, B, O; A.v = a; B.v = b;
#pragma unroll
  for (int j = 0; j < 8; j++) O.h[j] = f2bf(bf2f(A.h[j]) + bf2f(B.h[j]));
  return O.v;
}

// ------------------------- GroupNorm: stats pass ----------------------------
__global__ __launch_bounds__(256) void gn_stats_kernel(
    const float* __restrict__ x, float* __restrict__ part) {
  int c = blockIdx.x, b = blockIdx.y;
  int t = threadIdx.x, g = t & 31;
  const float* xb = x + (size_t)b * NTOK * CH + (size_t)c * 64 * CH + g * 16;
  float s = 0.f, q = 0.f;
  for (int p = 0; p < 8; p++) {
    const float* ptr = xb + ((size_t)p * 8 + (t >> 5)) * CH;
#pragma unroll
    for (int j = 0; j < 4; j++) {
      float4 v = *(const float4*)(ptr + j * 4);
      s += v.x + v.y + v.z + v.w;
      q += v.x * v.x + v.y * v.y + v.z * v.z + v.w * v.w;
    }
  }
  __shared__ float ls[32][8], lq[32][8];
  ls[g][t >> 5] = s; lq[g][t >> 5] = q;
  __syncthreads();
  if (t < 32) {
    float S = 0.f, Q = 0.f;
#pragma unroll
    for (int j = 0; j < 8; j++) { S += ls[t][j]; Q += lq[t][j]; }
    float2 o; o.x = S; o.y = Q;
    *(float2*)&part[(((size_t)b * 64 + c) * 32 + t) * 2] = o;
  }
}

// ------------------------- GroupNorm: apply pass ----------------------------
__global__ __launch_bounds__(256) void gn_apply_kernel(
    const float* __restrict__ x, const float* __restrict__ part,
    const float* __restrict__ gamma, const float* __restrict__ beta,
    u16* __restrict__ hn) {
  int blk = blockIdx.x, b = blk >> 9, t = threadIdx.x;
  __shared__ float msh[32], rsh[32];
  if (t < 64) {
    int g = t >> 1, half = t & 1;
    float S = 0.f, Q = 0.f;
    for (int c = half * 32; c < half * 32 + 32; c++) {
      float2 p = *(const float2*)&part[(((size_t)b * 64 + c) * 32 + g) * 2];
      S += p.x; Q += p.y;
    }
    S += __shfl_xor(S, 1, 64);
    Q += __shfl_xor(Q, 1, 64);
    if (half == 0) {
      float mean = S * (1.f / 65536.f);
      float var = Q * (1.f / 65536.f) - mean * mean;
      msh[g] = mean; rsh[g] = rsqrtf(var + 1e-5f);
    }
  }
  __syncthreads();
  size_t base = (size_t)b * NTOK * CH + (size_t)(blk & 511) * 4096 + t * 16;
  int ch0 = (t * 16) & 511;
  float mean = msh[t & 31], rstd = rsh[t & 31];
  const float* xp = x + base;
  union { u16 h[16]; uint4 v[2]; } o;
#pragma unroll
  for (int j = 0; j < 4; j++) {
    float4 xv = *(const float4*)(xp + j * 4);
    float4 gv = *(const float4*)(gamma + ch0 + j * 4);
    float4 bv = *(const float4*)(beta + ch0 + j * 4);
    o.h[j * 4 + 0] = f2bf((xv.x - mean) * rstd * gv.x + bv.x);
    o.h[j * 4 + 1] = f2bf((xv.y - mean) * rstd * gv.y + bv.y);
    o.h[j * 4 + 2] = f2bf((xv.z - mean) * rstd * gv.z + bv.z);
    o.h[j * 4 + 3] = f2bf((xv.w - mean) * rstd * gv.w + bv.w);
  }
  *(uint4*)(hn + base) = o.v[0];
  *(uint4*)(hn + base + 8) = o.v[1];
}

// ------------------- weight prep: fp32 [k][n] -> bf16 [n][k] ----------------
__global__ __launch_bounds__(256) void wprep_kernel(
    const float* w0, const float* w1, const float* w2, const float* w3,
    u16* t0, u16* t1, u16* t2, u16* t3) {
  int z = blockIdx.z;
  const float* w = z == 0 ? w0 : z == 1 ? w1 : z == 2 ? w2 : w3;
  u16* wt = z == 0 ? t0 : z == 1 ? t1 : z == 2 ? t2 : t3;
  __shared__ float tile[32][33];
  int k0 = blockIdx.x * 32, n0 = blockIdx.y * 32;
  int tx = threadIdx.x & 31, ty = threadIdx.x >> 5;
  for (int r = 0; r < 4; r++)
    tile[ty * 4 + r][tx] = w[(size_t)(k0 + ty * 4 + r) * CH + n0 + tx];
  __syncthreads();
  for (int r = 0; r < 4; r++)
    wt[(size_t)(n0 + ty * 4 + r) * CH + k0 + tx] = f2bf(tile[tx][ty * 4 + r]);
}

// ------------------------ merged q/k/v projection ---------------------------
// 128x128 tile over N=1536, BK=64, dbuf gload_lds. 4 waves (wx m-half, wy
// n-half), each 64x64 = 4x4 frags of 16x16x32 bf16.
// proj 0: qf8 (unscaled fp8), 1: kf8, 2: v -> fp8 transposed vtf8[b][c][n].
__global__ __launch_bounds__(256, 2) void qkv_gemm_kernel(
    const u16* __restrict__ A, const u16* __restrict__ Wcat,
    const float* __restrict__ bq, const float* __restrict__ bk,
    const float* __restrict__ bvv, u8* __restrict__ qf8, u8* __restrict__ kf8,
    u8* __restrict__ vtf8) {
  __shared__ __align__(16) u8 pool[65536];
  int m0 = blockIdx.x * 128, n0 = blockIdx.y * 128;
  int t = threadIdx.x, lane = t & 63, wave = t >> 6;
  int wx = wave & 1, wy = wave >> 1;
  int lane4 = lane >> 4;
  f32x4 acc[4][4] = {};                        // [mi(m)][ni(n)]
  const u16 *Asrc[4], *Bsrc[4];
  int dsto[4];
#pragma unroll
  for (int j = 0; j < 4; j++) {
    int u = t + j * 256, row = u >> 3, ch = (u & 7) ^ (row & 7);
    Asrc[j] = A + (size_t)(m0 + row) * CH + ch * 8;
    Bsrc[j] = Wcat + (size_t)(n0 + row) * CH + ch * 8;
    dsto[j] = u * 16;
  }
#pragma unroll
  for (int j = 0; j < 4; j++) {
    gload_lds16(Asrc[j], pool + dsto[j]);
    gload_lds16(Bsrc[j], pool + 32768 + dsto[j]);
  }
  __syncthreads();
  for (int kt = 0; kt < 8; kt++) {
    int co = (kt & 1) * 16384;
    const u16* Ac = (const u16*)(pool + co);
    const u16* Bc = (const u16*)(pool + 32768 + co);
    if (kt < 7) {
      int no = ((kt & 1) ^ 1) * 16384;
#pragma unroll
      for (int j = 0; j < 4; j++) {
        Asrc[j] += 64; Bsrc[j] += 64;
        gload_lds16(Asrc[j], pool + no + dsto[j]);
        gload_lds16(Bsrc[j], pool + 32768 + no + dsto[j]);
      }
    }
    __builtin_amdgcn_s_setprio(1);
#pragma unroll
    for (int ks = 0; ks < 2; ks++) {
      int kc = ks * 4 + lane4;
      s16x8 af[4], bf[4];
#pragma unroll
      for (int i = 0; i < 4; i++) {
        int ra = wx * 64 + i * 16 + (lane & 15);
        af[i] = *(const s16x8*)&Ac[ra * 64 + ((kc ^ (ra & 7)) << 3)];
        int rb = wy * 64 + i * 16 + (lane & 15);
        bf[i] = *(const s16x8*)&Bc[rb * 64 + ((kc ^ (rb & 7)) << 3)];
      }
#pragma unroll
      for (int mi = 0; mi < 4; mi++)
#pragma unroll
        for (int ni = 0; ni < 4; ni++)
          acc[mi][ni] = mfma16(af[mi], bf[ni], acc[mi][ni]);
    }
    __builtin_amdgcn_s_setprio(0);
    __syncthreads();
  }
  int proj = n0 >> 9;
  int r0l = wx * 64 + lane4 * 4;
  if (proj <= 1) {
    u8* O = proj == 0 ? qf8 : kf8;
    const float* bias = proj == 0 ? bq : bk;
#pragma unroll
    for (int mi = 0; mi < 4; mi++)
#pragma unroll
      for (int ni = 0; ni < 4; ni++) {
        int colp = (n0 & 511) + wy * 64 + ni * 16 + (lane & 15);
        float bv = bias[colp];
#pragma unroll
        for (int r = 0; r < 4; r++)
          O[(size_t)(m0 + r0l + mi * 16 + r) * CH + colp] =
              f2fp8(acc[mi][ni][r] + bv);
      }
  } else {
#pragma unroll
    for (int mi = 0; mi < 4; mi++)
#pragma unroll
      for (int ni = 0; ni < 4; ni++) {
        int colp = (n0 & 511) + wy * 64 + ni * 16 + (lane & 15);
        float bv = bvv[colp];
        int row = m0 + r0l + mi * 16;      // 4 consecutive token (n) rows
        int bb = row >> 12, nn = row & 4095;
        uint32_t p = pk_fp8x4(acc[mi][ni][0] + bv, acc[mi][ni][1] + bv,
                              acc[mi][ni][2] + bv, acc[mi][ni][3] + bv);
        *(uint32_t*)&vtf8[((size_t)bb * CH + colp) * NTOK + nn] = p;
      }
  }
}

// --------------- out projection GEMM (fuses part0+part1 add) ----------------
__global__ __launch_bounds__(256) void gemm_out_kernel(
    const u16* __restrict__ A, const u16* __restrict__ A2,
    const u16* __restrict__ Wt, const float* __restrict__ bias,
    float* __restrict__ out, const float* __restrict__ xres) {
  __shared__ __align__(16) u16 As[128 * 40];
  __shared__ __align__(16) u16 Bs[64 * 40];
  int m0 = blockIdx.x * 128, n0 = blockIdx.y * 64;
  int t = threadIdx.x, lane = t & 63, wave = t >> 6;
  int wm = wave >> 1, wn = wave & 1;
  f32x4 acc[4][2] = {};
  int arow = t >> 2, ac = t & 3;
  size_t aoff = (size_t)(m0 + arow) * CH + ac * 8;
  const u16* Bg = Wt + (size_t)(n0 + arow) * CH + ac * 8;
  uint4 a0 = addbf8(*(const uint4*)(A + aoff), *(const uint4*)(A2 + aoff));
  uint4 a1 = addbf8(*(const uint4*)(A + aoff + 64 * CH),
                    *(const uint4*)(A2 + aoff + 64 * CH));
  uint4 b0 = *(const uint4*)Bg;
  for (int kt = 0; kt < 16; kt++) {
    __syncthreads();
    *(uint4*)&As[(size_t)arow * 40 + ac * 8] = a0;
    *(uint4*)&As[(size_t)(arow + 64) * 40 + ac * 8] = a1;
    *(uint4*)&Bs[(size_t)arow * 40 + ac * 8] = b0;
    if (kt < 15) {
      aoff += 32; Bg += 32;
      a0 = addbf8(*(const uint4*)(A + aoff), *(const uint4*)(A2 + aoff));
      a1 = addbf8(*(const uint4*)(A + aoff + 64 * CH),
                  *(const uint4*)(A2 + aoff + 64 * CH));
      b0 = *(const uint4*)Bg;
    }
    __syncthreads();
    s16x8 af[4], bfr[2];
#pragma unroll
    for (int i = 0; i < 4; i++)
      af[i] = *(const s16x8*)&As[(wm * 64 + i * 16 + (lane & 15)) * 40 + (lane >> 4) * 8];
#pragma unroll
    for (int j = 0; j < 2; j++)
      bfr[j] = *(const s16x8*)&Bs[(wn * 32 + j * 16 + (lane & 15)) * 40 + (lane >> 4) * 8];
    __builtin_amdgcn_s_setprio(1);
#pragma unroll
    for (int mi = 0; mi < 4; mi++)
#pragma unroll
      for (int ni = 0; ni < 2; ni++)
        acc[mi][ni] = mfma16(af[mi], bfr[ni], acc[mi][ni]);
    __builtin_amdgcn_s_setprio(0);
  }
  int r0l = wm * 64 + ((lane >> 4) * 4);
  int c0l = wn * 32 + (lane & 15);
#pragma unroll
  for (int mi = 0; mi < 4; mi++)
#pragma unroll
    for (int ni = 0; ni < 2; ni++) {
      int col = n0 + c0l + ni * 16;
      float bv = bias[col];
#pragma unroll
      for (int r = 0; r < 4; r++) {
        size_t idx = (size_t)(m0 + r0l + mi * 16 + r) * CH + col;
        out[idx] = xres[idx] + acc[mi][ni][r] + bv;
      }
    }
}

// -------- K1: S = exp2(c*q·k^T) fp8 in/out, MX 32x32x64, dbuf, XCD-swz ------
// grid (32 m, 32 n, 2 b) remapped so each XCD owns 256 contiguous flat ids
// (all 32 m-panels x 8 n-panels x 1 batch) -> K-panels stay L2-resident.
__global__ __launch_bounds__(256, 2) void s_gemm_kernel(
    const u8* __restrict__ qf8, const u8* __restrict__ kf8,
    u8* __restrict__ S, float* __restrict__ lpart) {
  const float QSL2 = 0.06376275879949354f;     // (1/sqrt(512))*log2(e)
  __shared__ __align__(16) u8 pool[65536];
  int flat = blockIdx.x + 32 * blockIdx.y + 1024 * blockIdx.z;
  int remap = (flat & 7) * 256 + (flat >> 3);  // bijective (2048 % 8 == 0)
  int bx = remap & 31, by = (remap >> 5) & 31, bz = remap >> 10;
  const u8* qb = qf8 + (size_t)bz * NTOK * CH;
  const u8* kb = kf8 + (size_t)bz * NTOK * CH;
  u8* Sg = S + (size_t)bz * NTOK * NTOK;
  float* lp = lpart + (size_t)bz * 64 * NTOK;
  int m0 = bx * 128, n0 = by * 128;
  int t = threadIdx.x, lane = t & 63, wave = t >> 6;
  int wmx = wave & 1, wy = wave >> 1;          // wmx: m-half, wy: n-half
  int lh = lane >> 5;                          // k-half within fragment
  f32x16 acc[2][2] = {};                       // [ai(n-frag)][bj(m-frag)]
  const u8 *Asrc[4], *Bsrc[4];
  int dsto[4];
#pragma unroll
  for (int j = 0; j < 4; j++) {
    int u = t + j * 256, row = u >> 3, ch = (u & 7) ^ (row & 7);
    Asrc[j] = kb + (size_t)(n0 + row) * CH + ch * 16;
    Bsrc[j] = qb + (size_t)(m0 + row) * CH + ch * 16;
    dsto[j] = u * 16;
  }
#pragma unroll
  for (int j = 0; j < 4; j++) {
    gload_lds16(Asrc[j], pool + dsto[j]);
    gload_lds16(Bsrc[j], pool + 32768 + dsto[j]);
  }
  __syncthreads();
  for (int kt = 0; kt < 4; kt++) {
    int co = (kt & 1) * 16384;
    const u8* Ac = pool + co;
    const u8* Bc = pool + 32768 + co;
    if (kt < 3) {
      int no = ((kt & 1) ^ 1) * 16384;
#pragma unroll
      for (int j = 0; j < 4; j++) {
        Asrc[j] += 128; Bsrc[j] += 128;
        gload_lds16(Asrc[j], pool + no + dsto[j]);
        gload_lds16(Bsrc[j], pool + 32768 + no + dsto[j]);
      }
    }
    __builtin_amdgcn_s_setprio(1);
#pragma unroll
    for (int kh = 0; kh < 2; kh++) {           // K = 2 x 64 per 128B tile
      int cb = kh * 4 + lh * 2;
      union { i32x8 v; uint4 qq[2]; } bu[2];
#pragma unroll
      for (int bj = 0; bj < 2; bj++) {
        int rb = wmx * 64 + bj * 32 + (lane & 31);
        const u8* bp = &Bc[rb * 128];
        bu[bj].qq[0] = *(const uint4*)&bp[(cb ^ (rb & 7)) << 4];
        bu[bj].qq[1] = *(const uint4*)&bp[((cb + 1) ^ (rb & 7)) << 4];
      }
#pragma unroll
      for (int ai = 0; ai < 2; ai++) {
        int ra = wy * 64 + ai * 32 + (lane & 31);
        union { i32x8 v; uint4 qq[2]; } au;
        const u8* ap = &Ac[ra * 128];
        au.qq[0] = *(const uint4*)&ap[(cb ^ (ra & 7)) << 4];
        au.qq[1] = *(const uint4*)&ap[((cb + 1) ^ (ra & 7)) << 4];
#pragma unroll
        for (int bj = 0; bj < 2; bj++)
          acc[ai][bj] = mfma_mx8(au.v, bu[bj].v, acc[ai][bj]);
      }
    }
    __builtin_amdgcn_s_setprio(0);
    __syncthreads();
  }
  // ---- epilogue: exp2 -> fp8 u32 into swizzled LDS + lpart partials ----
  uint32_t* Stile = (uint32_t*)pool;           // [128][32] words = 16 KB
  float psum[2] = {};                          // per bj (m-frag)
#pragma unroll
  for (int ai = 0; ai < 2; ai++) {
#pragma unroll
    for (int bj = 0; bj < 2; bj++) {
      int ml = wmx * 64 + bj * 32 + (lane & 31);
#pragma unroll
      for (int qd = 0; qd < 4; qd++) {
        float e0 = exp2f(acc[ai][bj][qd * 4 + 0] * QSL2);
        float e1 = exp2f(acc[ai][bj][qd * 4 + 1] * QSL2);
        float e2 = exp2f(acc[ai][bj][qd * 4 + 2] * QSL2);
        float e3 = exp2f(acc[ai][bj][qd * 4 + 3] * QSL2);
        psum[bj] += e0 + e1 + e2 + e3;
        int nw = wy * 16 + ai * 8 + qd * 2 + lh;   // u32 word (4 consec n)
        Stile[ml * 32 + (nw ^ ((ml & 7) << 2))] = pk_fp8x4(e0, e1, e2, e3);
      }
    }
  }
#pragma unroll
  for (int bj = 0; bj < 2; bj++) {
    float v = psum[bj];
    v += __shfl_xor(v, 32, 64);                // combine lh halves
    if (lane < 32) {
      int m = m0 + wmx * 64 + bj * 32 + lane;
      lp[(size_t)((n0 >> 6) + wy) * NTOK + m] = v;
    }
  }
  __syncthreads();
  // ---- coalesced store: 8 threads/row cover the full 128B row ----
#pragma unroll
  for (int p = 0; p < 4; p++) {
    int row = (t >> 3) + p * 32;
    int g = t & 7;
    int w0 = (g * 4) ^ ((row & 7) << 2);       // 16B-group swizzle (contig 4)
    uint4 v;
    v.x = Stile[row * 32 + w0 + 0];
    v.y = Stile[row * 32 + w0 + 1];
    v.z = Stile[row * 32 + w0 + 2];
    v.w = Stile[row * 32 + w0 + 3];
    *(uint4*)&Sg[(size_t)(m0 + row) * NTOK + n0 + g * 16] = v;
  }
}

// ---- K2: O_s = P_s·V / l  (MX fp8 32x32x64, 4 waves x 64x64, fused linv) ---
__global__ __launch_bounds__(256, 2) void pv_gemm_kernel(
    const u8* __restrict__ S, const u8* __restrict__ vtf8,
    const float* __restrict__ lpart, u16* __restrict__ part0,
    u16* __restrict__ part1) {
  __shared__ __align__(16) u8 Asw[2][16384];
  __shared__ __align__(16) u8 Bsw[2][16384];
  __shared__ float linv_s[128];
  int flat = blockIdx.x + 32 * blockIdx.y + 128 * blockIdx.z;
  int xcd = flat & 7, u = flat >> 3;
  int m_t = xcd * 4 + (u & 3);
  int n_i = (u >> 2) & 3;
  int spb = u >> 4, sp = spb & 1, b = spb >> 1;
  int m0 = m_t * 128, n0 = n_i * 128, kbase = sp * 2048;
  const u8* Sb = S + (size_t)b * NTOK * NTOK;
  const u8* vb = vtf8 + (size_t)b * CH * NTOK;
  const float* lp = lpart + (size_t)b * 64 * NTOK;
  int t = threadIdx.x, lane = t & 63, wave = t >> 6;
  int wm = wave >> 1, wn = wave & 1;       // 2m x 2n waves, each 64m x 64n
  int lh = lane >> 5;
  f32x16 acc[2][2] = {};                   // [mi][ni]
  const u8 *Asrc[4], *Bsrc[4];
  int uoff[4];
#pragma unroll
  for (int j = 0; j < 4; j++) {
    int uu = t + j * 256, row = uu >> 3, ch = (uu & 7) ^ (row & 7);
    Asrc[j] = Sb + (size_t)(m0 + row) * NTOK + kbase + ch * 16;
    Bsrc[j] = vb + (size_t)(n0 + row) * NTOK + kbase + ch * 16;
    uoff[j] = uu * 16;
  }
#pragma unroll
  for (int j = 0; j < 4; j++) {
    gload_lds16(Asrc[j], &Asw[0][uoff[j]]);
    gload_lds16(Bsrc[j], &Bsw[0][uoff[j]]);
  }
  __syncthreads();
  int cur = 0;
  for (int kt = 0; kt < 16; kt++) {
    if (kt < 15) {
#pragma unroll
      for (int j = 0; j < 4; j++) {
        Asrc[j] += 128; Bsrc[j] += 128;
        gload_lds16(Asrc[j], &Asw[cur ^ 1][uoff[j]]);
        gload_lds16(Bsrc[j], &Bsw[cur ^ 1][uoff[j]]);
      }
    }
    __builtin_amdgcn_s_setprio(1);
#pragma unroll
    for (int kh = 0; kh < 2; kh++) {       // K = 2 x 64 per 128B tile
      int cb = kh * 4 + lh * 2;
      union { i32x8 v; uint4 qq[2]; } bu[2];
#pragma unroll
      for (int ni = 0; ni < 2; ni++) {
        int rb = wn * 64 + ni * 32 + (lane & 31);
        const u8* bp = &Bsw[cur][rb * 128];
        bu[ni].qq[0] = *(const uint4*)&bp[(cb ^ (rb & 7)) << 4];
        bu[ni].qq[1] = *(const uint4*)&bp[((cb + 1) ^ (rb & 7)) << 4];
      }
#pragma unroll
      for (int mi = 0; mi < 2; mi++) {
        int ra = wm * 64 + mi * 32 + (lane & 31);
        union { i32x8 v; uint4 qq[2]; } au;
        const u8* ap = &Asw[cur][ra * 128];
        au.qq[0] = *(const uint4*)&ap[(cb ^ (ra & 7)) << 4];
        au.qq[1] = *(const uint4*)&ap[((cb + 1) ^ (ra & 7)) << 4];
#pragma unroll
        for (int ni = 0; ni < 2; ni++)
          acc[mi][ni] = mfma_mx8(au.v, bu[ni].v, acc[mi][ni]);
      }
    }
    __builtin_amdgcn_s_setprio(0);
    __syncthreads();                       // drains prefetch vmcnt too
    cur ^= 1;
  }
  // ---- fused linv for this block's 128 rows (coalesced over lanes) ----
  if (t < 128) {
    float s = 0.f;
#pragma unroll 8
    for (int c = 0; c < 64; c++) s += lp[(size_t)c * NTOK + m0 + t];
    linv_s[t] = 1.f / s;
  }
  __syncthreads();
  u16* Od = (sp ? part1 : part0) + (size_t)b * NTOK * CH;
#pragma unroll
  for (int mi = 0; mi < 2; mi++)
#pragma unroll
    for (int ni = 0; ni < 2; ni++)
#pragma unroll
      for (int reg = 0; reg < 16; reg++) {
        int crow = (reg & 3) + 8 * (reg >> 2) + 4 * lh;
        int gr = wm * 64 + mi * 32 + crow;
        Od[(size_t)(m0 + gr) * CH + n0 + wn * 64 + ni * 32 + (lane & 31)] =
            f2bf(acc[mi][ni][reg] * linv_s[gr]);
      }
}

// ---------------------------------------------------------------------------
extern "C" void kernel_launch(void* const* d_in, const int* in_sizes, int n_in,
                              void* d_out, int out_size, void* d_ws, size_t ws_size,
                              hipStream_t stream) {
  const float* x     = (const float*)d_in[0];
  const float* gamma = (const float*)d_in[1];
  const float* beta  = (const float*)d_in[2];
  const float* wq    = (const float*)d_in[3];
  const float* bq    = (const float*)d_in[4];
  const float* wk    = (const float*)d_in[5];
  const float* bk    = (const float*)d_in[6];
  const float* wv    = (const float*)d_in[7];
  const float* bv    = (const float*)d_in[8];
  const float* wo    = (const float*)d_in[9];
  const float* bo    = (const float*)d_in[10];

  char* ws = (char*)d_ws;
  u16* hn   = (u16*)(ws + 0);                  // part0 / ao
  u16* q    = (u16*)(ws + 8388608);            // gnpart, then part1
  u8*  vtf8 = (u8*)(ws + 25165824);            // fp8 [2][512][4096] = 4 MiB
  u16* wqt  = (u16*)(ws + 33554432);           // wqt..wvt contiguous = wcat
  u16* wkt  = (u16*)(ws + 34078720);
  u16* wvt  = (u16*)(ws + 34603008);
  u16* wot  = (u16*)(ws + 35127296);
  u8*  S    = (u8*)(ws + 35651584);            // fp8 [2][4096][4096] = 32 MiB
  float* lpart = (float*)(ws + 71303168);      // [2][64][4096] f32 = 2 MiB
  u8*  qf8  = (u8*)(ws + 75497472);            // fp8 [2][4096][512] = 4 MiB
  u8*  kf8  = (u8*)(ws + 79691776);            // fp8 [2][4096][512] = 4 MiB

  float* gnpart = (float*)q;

  gn_stats_kernel<<<dim3(64, 2), 256, 0, stream>>>(x, gnpart);
  wprep_kernel<<<dim3(16, 16, 4), 256, 0, stream>>>(wq, wk, wv, wo, wqt, wkt, wvt, wot);
  gn_apply_kernel<<<1024, 256, 0, stream>>>(x, gnpart, gamma, beta, hn);
  qkv_gemm_kernel<<<dim3(64, 12), 256, 0, stream>>>(hn, wqt, bq, bk, bv, qf8, kf8, vtf8);
  s_gemm_kernel<<<dim3(32, 32, 2), 256, 0, stream>>>(qf8, kf8, S, lpart);
  pv_gemm_kernel<<<dim3(32, 4, 4), 256, 0, stream>>>(S, vtf8, lpart, hn, q);
  gemm_out_kernel<<<dim3(64, 8), 256, 0, stream>>>(hn, q, wot, bo, (float*)d_out, x);
}

// Round 17
// 114.599 us; speedup vs baseline: 1.0301x; 1.0301x over previous
//
#include <hip/hip_runtime.h>
#include <hip/hip_fp8.h>
#include <stdint.h>

// ---------------------------------------------------------------------------
// AttentionBlock: GroupNorm(32) -> q,k,v 1x1 conv -> full attention (N=4096,
// C=512, single head) -> out proj + residual.
// R17: exact R14 baseline + T4 counted-vmcnt pipelines in s_gemm and pv:
//      depth-2 prefetch, s_waitcnt vmcnt(8) (never 0 mid-loop), raw
//      s_barrier pairs, loads stay in flight across barriers.
// Workspace:
//   hn/part0/ao bf16 [2][4096][512] @ 0
//   q/part1     bf16 [2][4096][512] @ 8 MB   (gnpart early, part1 late)
//   vtf8        fp8  [2][512][4096] @ 24 MB
//   wqt..wot    bf16 [n][k]         @ 32 MB
//   S           fp8  [2][4096][4096]@ 34 MB  (32 MiB, exp'd)
//   lpart f32 [2][64][4096] @ 68 MB
//   qf8 fp8 [2][4096][512] @ 72 MB ; kf8 @ 76 MB
// ---------------------------------------------------------------------------

typedef unsigned short u16;
typedef unsigned char u8;
typedef short s16x8 __attribute__((ext_vector_type(8)));   // 8 bf16 bits
typedef float f32x4 __attribute__((ext_vector_type(4)));
typedef int i32x8 __attribute__((ext_vector_type(8)));
typedef float f32x16 __attribute__((ext_vector_type(16)));

#define NTOK 4096
#define CH   512

__device__ inline u16 f2bf(float f) {
  union { float f; uint32_t u; } v; v.f = f;
  uint32_t r = v.u + 0x7FFFu + ((v.u >> 16) & 1u);   // RNE
  return (u16)(r >> 16);
}
__device__ inline float bf2f(u16 b) {
  union { uint32_t u; float f; } v; v.u = (uint32_t)b << 16; return v.f;
}
__device__ inline f32x4 mfma16(s16x8 a, s16x8 b, f32x4 c) {
  return __builtin_amdgcn_mfma_f32_16x16x32_bf16(a, b, c, 0, 0, 0);
}
// block-scaled fp8 MFMA, scales = 1.0 (E8M0 bias 127) -> plain fp8 GEMM at 2x rate
__device__ inline f32x16 mfma_mx8(i32x8 a, i32x8 b, f32x16 c) {
  return __builtin_amdgcn_mfma_scale_f32_32x32x64_f8f6f4(
      a, b, c, 0 /*cbsz=fp8*/, 0 /*blgp=fp8*/,
      0, 0x7F7F7F7F, 0, 0x7F7F7F7F);
}
// pack 4 floats -> 4 fp8 e4m3 bytes (saturating)
__device__ inline uint32_t pk_fp8x4(float e0, float e1, float e2, float e3) {
#if __has_builtin(__builtin_amdgcn_cvt_pk_fp8_f32)
  int v = __builtin_amdgcn_cvt_pk_fp8_f32(e0, e1, 0, false);
  v = __builtin_amdgcn_cvt_pk_fp8_f32(e2, e3, v, true);
  return (uint32_t)v;
#else
  __hip_fp8_e4m3 a(e0), b(e1), c(e2), d(e3);
  return (uint32_t)*(u8*)&a | ((uint32_t)*(u8*)&b << 8) |
         ((uint32_t)*(u8*)&c << 16) | ((uint32_t)*(u8*)&d << 24);
#endif
}
__device__ inline u8 f2fp8(float x) {
#if __has_builtin(__builtin_amdgcn_cvt_pk_fp8_f32)
  int v = __builtin_amdgcn_cvt_pk_fp8_f32(x, x, 0, false);
  return (u8)(v & 0xFF);
#else
  __hip_fp8_e4m3 h(x); return *(u8*)&h;
#endif
}
// global -> LDS direct 16B copy (dest = wave-uniform base + lane*16)
__device__ inline void gload_lds16(const void* g, void* l) {
  __builtin_amdgcn_global_load_lds(
      (const __attribute__((address_space(1))) unsigned*)g,
      (__attribute__((address_space(3))) unsigned*)l, 16, 0, 0);
}
__device__ inline uint4 addbf8(uint4 a, uint4 b) {
  union { uint4 v; u16 h[8]; } A, B, O; A.v = a; B.v = b;
#pragma unroll
  for (int j = 0; j < 8; j++) O.h[j] = f2bf(bf2f(A.h[j]) + bf2f(B.h[j]));
  return O.v;
}
// counted-vmcnt pipeline primitives (T4): never drain to 0 mid-loop
__device__ inline void wait_vm8() {
  asm volatile("s_waitcnt vmcnt(8)" ::: "memory");
  __builtin_amdgcn_sched_barrier(0);
}
__device__ inline void wait_vm0() {
  asm volatile("s_waitcnt vmcnt(0)" ::: "memory");
  __builtin_amdgcn_sched_barrier(0);
}
__device__ inline void barrier_raw() {
  __builtin_amdgcn_sched_barrier(0);
  __builtin_amdgcn_s_barrier();
  __builtin_amdgcn_sched_barrier(0);
}

// ------------------------- GroupNorm: stats pass ----------------------------
__global__ __launch_bounds__(256) void gn_stats_kernel(
    const float* __restrict__ x, float* __restrict__ part) {
  int c = blockIdx.x, b = blockIdx.y;
  int t = threadIdx.x, g = t & 31;
  const float* xb = x + (size_t)b * NTOK * CH + (size_t)c * 64 * CH + g * 16;
  float s = 0.f, q = 0.f;
  for (int p = 0; p < 8; p++) {
    const float* ptr = xb + ((size_t)p * 8 + (t >> 5)) * CH;
#pragma unroll
    for (int j = 0; j < 4; j++) {
      float4 v = *(const float4*)(ptr + j * 4);
      s += v.x + v.y + v.z + v.w;
      q += v.x * v.x + v.y * v.y + v.z * v.z + v.w * v.w;
    }
  }
  __shared__ float ls[32][8], lq[32][8];
  ls[g][t >> 5] = s; lq[g][t >> 5] = q;
  __syncthreads();
  if (t < 32) {
    float S = 0.f, Q = 0.f;
#pragma unroll
    for (int j = 0; j < 8; j++) { S += ls[t][j]; Q += lq[t][j]; }
    float2 o; o.x = S; o.y = Q;
    *(float2*)&part[(((size_t)b * 64 + c) * 32 + t) * 2] = o;
  }
}

// ------------------------- GroupNorm: apply pass ----------------------------
__global__ __launch_bounds__(256) void gn_apply_kernel(
    const float* __restrict__ x, const float* __restrict__ part,
    const float* __restrict__ gamma, const float* __restrict__ beta,
    u16* __restrict__ hn) {
  int blk = blockIdx.x, b = blk >> 9, t = threadIdx.x;
  __shared__ float msh[32], rsh[32];
  if (t < 64) {
    int g = t >> 1, half = t & 1;
    float S = 0.f, Q = 0.f;
    for (int c = half * 32; c < half * 32 + 32; c++) {
      float2 p = *(const float2*)&part[(((size_t)b * 64 + c) * 32 + g) * 2];
      S += p.x; Q += p.y;
    }
    S += __shfl_xor(S, 1, 64);
    Q += __shfl_xor(Q, 1, 64);
    if (half == 0) {
      float mean = S * (1.f / 65536.f);
      float var = Q * (1.f / 65536.f) - mean * mean;
      msh[g] = mean; rsh[g] = rsqrtf(var + 1e-5f);
    }
  }
  __syncthreads();
  size_t base = (size_t)b * NTOK * CH + (size_t)(blk & 511) * 4096 + t * 16;
  int ch0 = (t * 16) & 511;
  float mean = msh[t & 31], rstd = rsh[t & 31];
  const float* xp = x + base;
  union { u16 h[16]; uint4 v[2]; } o;
#pragma unroll
  for (int j = 0; j < 4; j++) {
    float4 xv = *(const float4*)(xp + j * 4);
    float4 gv = *(const float4*)(gamma + ch0 + j * 4);
    float4 bv = *(const float4*)(beta + ch0 + j * 4);
    o.h[j * 4 + 0] = f2bf((xv.x - mean) * rstd * gv.x + bv.x);
    o.h[j * 4 + 1] = f2bf((xv.y - mean) * rstd * gv.y + bv.y);
    o.h[j * 4 + 2] = f2bf((xv.z - mean) * rstd * gv.z + bv.z);
    o.h[j * 4 + 3] = f2bf((xv.w - mean) * rstd * gv.w + bv.w);
  }
  *(uint4*)(hn + base) = o.v[0];
  *(uint4*)(hn + base + 8) = o.v[1];
}

// ------------------- weight prep: fp32 [k][n] -> bf16 [n][k] ----------------
__global__ __launch_bounds__(256) void wprep_kernel(
    const float* w0, const float* w1, const float* w2, const float* w3,
    u16* t0, u16* t1, u16* t2, u16* t3) {
  int z = blockIdx.z;
  const float* w = z == 0 ? w0 : z == 1 ? w1 : z == 2 ? w2 : w3;
  u16* wt = z == 0 ? t0 : z == 1 ? t1 : z == 2 ? t2 : t3;
  __shared__ float tile[32][33];
  int k0 = blockIdx.x * 32, n0 = blockIdx.y * 32;
  int tx = threadIdx.x & 31, ty = threadIdx.x >> 5;
  for (int r = 0; r < 4; r++)
    tile[ty * 4 + r][tx] = w[(size_t)(k0 + ty * 4 + r) * CH + n0 + tx];
  __syncthreads();
  for (int r = 0; r < 4; r++)
    wt[(size_t)(n0 + ty * 4 + r) * CH + k0 + tx] = f2bf(tile[tx][ty * 4 + r]);
}

// ------------------------ merged q/k/v projection ---------------------------
// 128x128 tile over N=1536, BK=64, dbuf gload_lds. 4 waves (wx m-half, wy
// n-half), each 64x64 = 4x4 frags of 16x16x32 bf16.
// proj 0: qf8 (unscaled fp8), 1: kf8, 2: v -> fp8 transposed vtf8[b][c][n].
__global__ __launch_bounds__(256, 2) void qkv_gemm_kernel(
    const u16* __restrict__ A, const u16* __restrict__ Wcat,
    const float* __restrict__ bq, const float* __restrict__ bk,
    const float* __restrict__ bvv, u8* __restrict__ qf8, u8* __restrict__ kf8,
    u8* __restrict__ vtf8) {
  __shared__ __align__(16) u8 pool[65536];
  int m0 = blockIdx.x * 128, n0 = blockIdx.y * 128;
  int t = threadIdx.x, lane = t & 63, wave = t >> 6;
  int wx = wave & 1, wy = wave >> 1;
  int lane4 = lane >> 4;
  f32x4 acc[4][4] = {};                        // [mi(m)][ni(n)]
  const u16 *Asrc[4], *Bsrc[4];
  int dsto[4];
#pragma unroll
  for (int j = 0; j < 4; j++) {
    int u = t + j * 256, row = u >> 3, ch = (u & 7) ^ (row & 7);
    Asrc[j] = A + (size_t)(m0 + row) * CH + ch * 8;
    Bsrc[j] = Wcat + (size_t)(n0 + row) * CH + ch * 8;
    dsto[j] = u * 16;
  }
#pragma unroll
  for (int j = 0; j < 4; j++) {
    gload_lds16(Asrc[j], pool + dsto[j]);
    gload_lds16(Bsrc[j], pool + 32768 + dsto[j]);
  }
  __syncthreads();
  for (int kt = 0; kt < 8; kt++) {
    int co = (kt & 1) * 16384;
    const u16* Ac = (const u16*)(pool + co);
    const u16* Bc = (const u16*)(pool + 32768 + co);
    if (kt < 7) {
      int no = ((kt & 1) ^ 1) * 16384;
#pragma unroll
      for (int j = 0; j < 4; j++) {
        Asrc[j] += 64; Bsrc[j] += 64;
        gload_lds16(Asrc[j], pool + no + dsto[j]);
        gload_lds16(Bsrc[j], pool + 32768 + no + dsto[j]);
      }
    }
    __builtin_amdgcn_s_setprio(1);
#pragma unroll
    for (int ks = 0; ks < 2; ks++) {
      int kc = ks * 4 + lane4;
      s16x8 af[4], bf[4];
#pragma unroll
      for (int i = 0; i < 4; i++) {
        int ra = wx * 64 + i * 16 + (lane & 15);
        af[i] = *(const s16x8*)&Ac[ra * 64 + ((kc ^ (ra & 7)) << 3)];
        int rb = wy * 64 + i * 16 + (lane & 15);
        bf[i] = *(const s16x8*)&Bc[rb * 64 + ((kc ^ (rb & 7)) << 3)];
      }
#pragma unroll
      for (int mi = 0; mi < 4; mi++)
#pragma unroll
        for (int ni = 0; ni < 4; ni++)
          acc[mi][ni] = mfma16(af[mi], bf[ni], acc[mi][ni]);
    }
    __builtin_amdgcn_s_setprio(0);
    __syncthreads();
  }
  int proj = n0 >> 9;
  int r0l = wx * 64 + lane4 * 4;
  if (proj <= 1) {
    u8* O = proj == 0 ? qf8 : kf8;
    const float* bias = proj == 0 ? bq : bk;
#pragma unroll
    for (int mi = 0; mi < 4; mi++)
#pragma unroll
      for (int ni = 0; ni < 4; ni++) {
        int colp = (n0 & 511) + wy * 64 + ni * 16 + (lane & 15);
        float bv = bias[colp];
#pragma unroll
        for (int r = 0; r < 4; r++)
          O[(size_t)(m0 + r0l + mi * 16 + r) * CH + colp] =
              f2fp8(acc[mi][ni][r] + bv);
      }
  } else {
#pragma unroll
    for (int mi = 0; mi < 4; mi++)
#pragma unroll
      for (int ni = 0; ni < 4; ni++) {
        int colp = (n0 & 511) + wy * 64 + ni * 16 + (lane & 15);
        float bv = bvv[colp];
        int row = m0 + r0l + mi * 16;      // 4 consecutive token (n) rows
        int bb = row >> 12, nn = row & 4095;
        uint32_t p = pk_fp8x4(acc[mi][ni][0] + bv, acc[mi][ni][1] + bv,
                              acc[mi][ni][2] + bv, acc[mi][ni][3] + bv);
        *(uint32_t*)&vtf8[((size_t)bb * CH + colp) * NTOK + nn] = p;
      }
  }
}

// --------------- out projection GEMM (fuses part0+part1 add) ----------------
__global__ __launch_bounds__(256) void gemm_out_kernel(
    const u16* __restrict__ A, const u16* __restrict__ A2,
    const u16* __restrict__ Wt, const float* __restrict__ bias,
    float* __restrict__ out, const float* __restrict__ xres) {
  __shared__ __align__(16) u16 As[128 * 40];
  __shared__ __align__(16) u16 Bs[64 * 40];
  int m0 = blockIdx.x * 128, n0 = blockIdx.y * 64;
  int t = threadIdx.x, lane = t & 63, wave = t >> 6;
  int wm = wave >> 1, wn = wave & 1;
  f32x4 acc[4][2] = {};
  int arow = t >> 2, ac = t & 3;
  size_t aoff = (size_t)(m0 + arow) * CH + ac * 8;
  const u16* Bg = Wt + (size_t)(n0 + arow) * CH + ac * 8;
  uint4 a0 = addbf8(*(const uint4*)(A + aoff), *(const uint4*)(A2 + aoff));
  uint4 a1 = addbf8(*(const uint4*)(A + aoff + 64 * CH),
                    *(const uint4*)(A2 + aoff + 64 * CH));
  uint4 b0 = *(const uint4*)Bg;
  for (int kt = 0; kt < 16; kt++) {
    __syncthreads();
    *(uint4*)&As[(size_t)arow * 40 + ac * 8] = a0;
    *(uint4*)&As[(size_t)(arow + 64) * 40 + ac * 8] = a1;
    *(uint4*)&Bs[(size_t)arow * 40 + ac * 8] = b0;
    if (kt < 15) {
      aoff += 32; Bg += 32;
      a0 = addbf8(*(const uint4*)(A + aoff), *(const uint4*)(A2 + aoff));
      a1 = addbf8(*(const uint4*)(A + aoff + 64 * CH),
                  *(const uint4*)(A2 + aoff + 64 * CH));
      b0 = *(const uint4*)Bg;
    }
    __syncthreads();
    s16x8 af[4], bfr[2];
#pragma unroll
    for (int i = 0; i < 4; i++)
      af[i] = *(const s16x8*)&As[(wm * 64 + i * 16 + (lane & 15)) * 40 + (lane >> 4) * 8];
#pragma unroll
    for (int j = 0; j < 2; j++)
      bfr[j] = *(const s16x8*)&Bs[(wn * 32 + j * 16 + (lane & 15)) * 40 + (lane >> 4) * 8];
    __builtin_amdgcn_s_setprio(1);
#pragma unroll
    for (int mi = 0; mi < 4; mi++)
#pragma unroll
      for (int ni = 0; ni < 2; ni++)
        acc[mi][ni] = mfma16(af[mi], bfr[ni], acc[mi][ni]);
    __builtin_amdgcn_s_setprio(0);
  }
  int r0l = wm * 64 + ((lane >> 4) * 4);
  int c0l = wn * 32 + (lane & 15);
#pragma unroll
  for (int mi = 0; mi < 4; mi++)
#pragma unroll
    for (int ni = 0; ni < 2; ni++) {
      int col = n0 + c0l + ni * 16;
      float bv = bias[col];
#pragma unroll
      for (int r = 0; r < 4; r++) {
        size_t idx = (size_t)(m0 + r0l + mi * 16 + r) * CH + col;
        out[idx] = xres[idx] + acc[mi][ni][r] + bv;
      }
    }
}

// -- K1: S = exp(qscale*q·k^T) fp8 in/out, MX 32x32x64, counted-vmcnt pipe ---
// grid (32 m, 32 n, 2 b), 256 thr = 4 waves (wmx m-half, wy n-half).
// Depth-2 prefetch, 8 loads/tile/wave; vmcnt(8) before each compute (vmcnt(0)
// only on the final tile); raw s_barrier pairs keep loads in flight.
__global__ __launch_bounds__(256, 2) void s_gemm_kernel(
    const u8* __restrict__ qf8, const u8* __restrict__ kf8,
    u8* __restrict__ S, float* __restrict__ lpart) {
  const float QS = 0.044194173824159216f;      // 1/sqrt(512)
  __shared__ __align__(16) u8 pool[65536];
  int bz = blockIdx.z;
  const u8* qb = qf8 + (size_t)bz * NTOK * CH;
  const u8* kb = kf8 + (size_t)bz * NTOK * CH;
  u8* Sg = S + (size_t)bz * NTOK * NTOK;
  float* lp = lpart + (size_t)bz * 64 * NTOK;
  int m0 = blockIdx.x * 128, n0 = blockIdx.y * 128;
  int t = threadIdx.x, lane = t & 63, wave = t >> 6;
  int wmx = wave & 1, wy = wave >> 1;          // wmx: m-half, wy: n-half
  int lh = lane >> 5;                          // k-half within fragment
  f32x16 acc[2][2] = {};                       // [ai(n-frag)][bj(m-frag)]
  const u8 *Asrc[4], *Bsrc[4];
  int dsto[4];
#pragma unroll
  for (int j = 0; j < 4; j++) {
    int u = t + j * 256, row = u >> 3, ch = (u & 7) ^ (row & 7);
    Asrc[j] = kb + (size_t)(n0 + row) * CH + ch * 16;
    Bsrc[j] = qb + (size_t)(m0 + row) * CH + ch * 16;
    dsto[j] = u * 16;
  }
  // prologue: issue tiles 0 and 1 (16 loads in flight per wave)
#pragma unroll
  for (int j = 0; j < 4; j++) {
    gload_lds16(Asrc[j], pool + dsto[j]);
    gload_lds16(Bsrc[j], pool + 32768 + dsto[j]);
  }
#pragma unroll
  for (int j = 0; j < 4; j++) {
    Asrc[j] += 128; Bsrc[j] += 128;
    gload_lds16(Asrc[j], pool + 16384 + dsto[j]);
    gload_lds16(Bsrc[j], pool + 32768 + 16384 + dsto[j]);
  }
  __builtin_amdgcn_sched_barrier(0);
#pragma unroll
  for (int kt = 0; kt < 4; kt++) {
    if (kt < 3) wait_vm8(); else wait_vm0();   // my tile-kt loads done
    barrier_raw();                             // everyone's tile-kt landed
    int co = (kt & 1) * 16384;
    const u8* Ac = pool + co;
    const u8* Bc = pool + 32768 + co;
    __builtin_amdgcn_s_setprio(1);
#pragma unroll
    for (int kh = 0; kh < 2; kh++) {           // K = 2 x 64 per 128B tile
      int cb = kh * 4 + lh * 2;
      union { i32x8 v; uint4 qq[2]; } bu[2];
#pragma unroll
      for (int bj = 0; bj < 2; bj++) {
        int rb = wmx * 64 + bj * 32 + (lane & 31);
        const u8* bp = &Bc[rb * 128];
        bu[bj].qq[0] = *(const uint4*)&bp[(cb ^ (rb & 7)) << 4];
        bu[bj].qq[1] = *(const uint4*)&bp[((cb + 1) ^ (rb & 7)) << 4];
      }
#pragma unroll
      for (int ai = 0; ai < 2; ai++) {
        int ra = wy * 64 + ai * 32 + (lane & 31);
        union { i32x8 v; uint4 qq[2]; } au;
        const u8* ap = &Ac[ra * 128];
        au.qq[0] = *(const uint4*)&ap[(cb ^ (ra & 7)) << 4];
        au.qq[1] = *(const uint4*)&ap[((cb + 1) ^ (ra & 7)) << 4];
#pragma unroll
        for (int bj = 0; bj < 2; bj++)
          acc[ai][bj] = mfma_mx8(au.v, bu[bj].v, acc[ai][bj]);
      }
    }
    __builtin_amdgcn_s_setprio(0);
    barrier_raw();                             // all waves done reading buf
    if (kt < 2) {                              // issue tile kt+2 into buf
#pragma unroll
      for (int j = 0; j < 4; j++) {
        Asrc[j] += 128; Bsrc[j] += 128;
        gload_lds16(Asrc[j], pool + co + dsto[j]);
        gload_lds16(Bsrc[j], pool + 32768 + co + dsto[j]);
      }
    }
  }
  // ---- epilogue: exp -> fp8 u32 into swizzled LDS + lpart partials ----
  uint32_t* Stile = (uint32_t*)pool;           // [128][32] words = 16 KB
  float psum[2] = {};                          // per bj (m-frag)
#pragma unroll
  for (int ai = 0; ai < 2; ai++) {
#pragma unroll
    for (int bj = 0; bj < 2; bj++) {
      int ml = wmx * 64 + bj * 32 + (lane & 31);
#pragma unroll
      for (int qd = 0; qd < 4; qd++) {
        float e0 = __expf(acc[ai][bj][qd * 4 + 0] * QS);
        float e1 = __expf(acc[ai][bj][qd * 4 + 1] * QS);
        float e2 = __expf(acc[ai][bj][qd * 4 + 2] * QS);
        float e3 = __expf(acc[ai][bj][qd * 4 + 3] * QS);
        psum[bj] += e0 + e1 + e2 + e3;
        int nw = wy * 16 + ai * 8 + qd * 2 + lh;   // u32 word (4 consec n)
        Stile[ml * 32 + (nw ^ ((ml & 7) << 2))] = pk_fp8x4(e0, e1, e2, e3);
      }
    }
  }
#pragma unroll
  for (int bj = 0; bj < 2; bj++) {
    float v = psum[bj];
    v += __shfl_xor(v, 32, 64);                // combine lh halves
    if (lane < 32) {
      int m = m0 + wmx * 64 + bj * 32 + lane;
      lp[(size_t)((n0 >> 6) + wy) * NTOK + m] = v;
    }
  }
  __syncthreads();
  // ---- coalesced store: 8 threads/row cover the full 128B row ----
#pragma unroll
  for (int p = 0; p < 4; p++) {
    int row = (t >> 3) + p * 32;
    int g = t & 7;
    int w0 = (g * 4) ^ ((row & 7) << 2);       // 16B-group swizzle (contig 4)
    uint4 v;
    v.x = Stile[row * 32 + w0 + 0];
    v.y = Stile[row * 32 + w0 + 1];
    v.z = Stile[row * 32 + w0 + 2];
    v.w = Stile[row * 32 + w0 + 3];
    *(uint4*)&Sg[(size_t)(m0 + row) * NTOK + n0 + g * 16] = v;
  }
}

// ---- K2: O_s = P_s·V / l  (MX fp8, 4 waves x 64x64, counted-vmcnt pipe) ----
__global__ __launch_bounds__(256, 2) void pv_gemm_kernel(
    const u8* __restrict__ S, const u8* __restrict__ vtf8,
    const float* __restrict__ lpart, u16* __restrict__ part0,
    u16* __restrict__ part1) {
  __shared__ __align__(16) u8 Asw[2][16384];
  __shared__ __align__(16) u8 Bsw[2][16384];
  __shared__ float linv_s[128];
  int flat = blockIdx.x + 32 * blockIdx.y + 128 * blockIdx.z;
  int xcd = flat & 7, u = flat >> 3;
  int m_t = xcd * 4 + (u & 3);
  int n_i = (u >> 2) & 3;
  int spb = u >> 4, sp = spb & 1, b = spb >> 1;
  int m0 = m_t * 128, n0 = n_i * 128, kbase = sp * 2048;
  const u8* Sb = S + (size_t)b * NTOK * NTOK;
  const u8* vb = vtf8 + (size_t)b * CH * NTOK;
  const float* lp = lpart + (size_t)b * 64 * NTOK;
  int t = threadIdx.x, lane = t & 63, wave = t >> 6;
  int wm = wave >> 1, wn = wave & 1;       // 2m x 2n waves, each 64m x 64n
  int lh = lane >> 5;
  f32x16 acc[2][2] = {};                   // [mi][ni]
  const u8 *Asrc[4], *Bsrc[4];
  int uoff[4];
#pragma unroll
  for (int j = 0; j < 4; j++) {
    int uu = t + j * 256, row = uu >> 3, ch = (uu & 7) ^ (row & 7);
    Asrc[j] = Sb + (size_t)(m0 + row) * NTOK + kbase + ch * 16;
    Bsrc[j] = vb + (size_t)(n0 + row) * NTOK + kbase + ch * 16;
    uoff[j] = uu * 16;
  }
  // prologue: issue tiles 0 and 1
#pragma unroll
  for (int j = 0; j < 4; j++) {
    gload_lds16(Asrc[j], &Asw[0][uoff[j]]);
    gload_lds16(Bsrc[j], &Bsw[0][uoff[j]]);
  }
#pragma unroll
  for (int j = 0; j < 4; j++) {
    Asrc[j] += 128; Bsrc[j] += 128;
    gload_lds16(Asrc[j], &Asw[1][uoff[j]]);
    gload_lds16(Bsrc[j], &Bsw[1][uoff[j]]);
  }
  __builtin_amdgcn_sched_barrier(0);
  for (int kt = 0; kt < 16; kt++) {
    if (kt < 15) wait_vm8(); else wait_vm0();
    barrier_raw();
    int cur = kt & 1;
    __builtin_amdgcn_s_setprio(1);
#pragma unroll
    for (int kh = 0; kh < 2; kh++) {       // K = 2 x 64 per 128B tile
      int cb = kh * 4 + lh * 2;
      union { i32x8 v; uint4 qq[2]; } bu[2];
#pragma unroll
      for (int ni = 0; ni < 2; ni++) {
        int rb = wn * 64 + ni * 32 + (lane & 31);
        const u8* bp = &Bsw[cur][rb * 128];
        bu[ni].qq[0] = *(const uint4*)&bp[(cb ^ (rb & 7)) << 4];
        bu[ni].qq[1] = *(const uint4*)&bp[((cb + 1) ^ (rb & 7)) << 4];
      }
#pragma unroll
      for (int mi = 0; mi < 2; mi++) {
        int ra = wm * 64 + mi * 32 + (lane & 31);
        union { i32x8 v; uint4 qq[2]; } au;
        const u8* ap = &Asw[cur][ra * 128];
        au.qq[0] = *(const uint4*)&ap[(cb ^ (ra & 7)) << 4];
        au.qq[1] = *(const uint4*)&ap[((cb + 1) ^ (ra & 7)) << 4];
#pragma unroll
        for (int ni = 0; ni < 2; ni++)
          acc[mi][ni] = mfma_mx8(au.v, bu[ni].v, acc[mi][ni]);
      }
    }
    __builtin_amdgcn_s_setprio(0);
    barrier_raw();
    if (kt < 14) {                         // issue tile kt+2 into buf cur
#pragma unroll
      for (int j = 0; j < 4; j++) {
        Asrc[j] += 128; Bsrc[j] += 128;
        gload_lds16(Asrc[j], &Asw[cur][uoff[j]]);
        gload_lds16(Bsrc[j], &Bsw[cur][uoff[j]]);
      }
    }
  }
  // ---- fused linv for this block's 128 rows (coalesced over lanes) ----
  if (t < 128) {
    float s = 0.f;
#pragma unroll 8
    for (int c = 0; c < 64; c++) s += lp[(size_t)c * NTOK + m0 + t];
    linv_s[t] = 1.f / s;
  }
  __syncthreads();
  u16* Od = (sp ? part1 : part0) + (size_t)b * NTOK * CH;
#pragma unroll
  for (int mi = 0; mi < 2; mi++)
#pragma unroll
    for (int ni = 0; ni < 2; ni++)
#pragma unroll
      for (int reg = 0; reg < 16; reg++) {
        int crow = (reg & 3) + 8 * (reg >> 2) + 4 * lh;
        int gr = wm * 64 + mi * 32 + crow;
        Od[(size_t)(m0 + gr) * CH + n0 + wn * 64 + ni * 32 + (lane & 31)] =
            f2bf(acc[mi][ni][reg] * linv_s[gr]);
      }
}

// ---------------------------------------------------------------------------
extern "C" void kernel_launch(void* const* d_in, const int* in_sizes, int n_in,
                              void* d_out, int out_size, void* d_ws, size_t ws_size,
                              hipStream_t stream) {
  const float* x     = (const float*)d_in[0];
  const float* gamma = (const float*)d_in[1];
  const float* beta  = (const float*)d_in[2];
  const float* wq    = (const float*)d_in[3];
  const float* bq    = (const float*)d_in[4];
  const float* wk    = (const float*)d_in[5];
  const float* bk    = (const float*)d_in[6];
  const float* wv    = (const float*)d_in[7];
  const float* bv    = (const float*)d_in[8];
  const float* wo    = (const float*)d_in[9];
  const float* bo    = (const float*)d_in[10];

  char* ws = (char*)d_ws;
  u16* hn   = (u16*)(ws + 0);                  // part0 / ao
  u16* q    = (u16*)(ws + 8388608);            // gnpart, then part1
  u8*  vtf8 = (u8*)(ws + 25165824);            // fp8 [2][512][4096] = 4 MiB
  u16* wqt  = (u16*)(ws + 33554432);           // wqt..wvt contiguous = wcat
  u16* wkt  = (u16*)(ws + 34078720);
  u16* wvt  = (u16*)(ws + 34603008);
  u16* wot  = (u16*)(ws + 35127296);
  u8*  S    = (u8*)(ws + 35651584);            // fp8 [2][4096][4096] = 32 MiB
  float* lpart = (float*)(ws + 71303168);      // [2][64][4096] f32 = 2 MiB
  u8*  qf8  = (u8*)(ws + 75497472);            // fp8 [2][4096][512] = 4 MiB
  u8*  kf8  = (u8*)(ws + 79691776);            // fp8 [2][4096][512] = 4 MiB

  float* gnpart = (float*)q;

  gn_stats_kernel<<<dim3(64, 2), 256, 0, stream>>>(x, gnpart);
  wprep_kernel<<<dim3(16, 16, 4), 256, 0, stream>>>(wq, wk, wv, wo, wqt, wkt, wvt, wot);
  gn_apply_kernel<<<1024, 256, 0, stream>>>(x, gnpart, gamma, beta, hn);
  qkv_gemm_kernel<<<dim3(64, 12), 256, 0, stream>>>(hn, wqt, bq, bk, bv, qf8, kf8, vtf8);
  s_gemm_kernel<<<dim3(32, 32, 2), 256, 0, stream>>>(qf8, kf8, S, lpart);
  pv_gemm_kernel<<<dim3(32, 4, 4), 256, 0, stream>>>(S, vtf8, lpart, hn, q);
  gemm_out_kernel<<<dim3(64, 8), 256, 0, stream>>>(hn, q, wot, bo, (float*)d_out, x);
}

// Round 18
// 111.990 us; speedup vs baseline: 1.0541x; 1.0233x over previous
//
#include <hip/hip_runtime.h>
#include <hip/hip_fp8.h>
#include <stdint.h>

// ---------------------------------------------------------------------------
// AttentionBlock: GroupNorm(32) -> q,k,v 1x1 conv -> full attention (N=4096,
// C=512, single head) -> out proj + residual.
// R18: R17 + gn_stats and wprep fused into one launch (prologue kernel);
//      removes one launch gap and lets GN stats and weight prep co-run.
// Workspace:
//   hn/part0/ao bf16 [2][4096][512] @ 0
//   q/part1     bf16 [2][4096][512] @ 8 MB   (gnpart early, part1 late)
//   vtf8        fp8  [2][512][4096] @ 24 MB
//   wqt..wot    bf16 [n][k]         @ 32 MB
//   S           fp8  [2][4096][4096]@ 34 MB  (32 MiB, exp'd)
//   lpart f32 [2][64][4096] @ 68 MB
//   qf8 fp8 [2][4096][512] @ 72 MB ; kf8 @ 76 MB
// ---------------------------------------------------------------------------

typedef unsigned short u16;
typedef unsigned char u8;
typedef short s16x8 __attribute__((ext_vector_type(8)));   // 8 bf16 bits
typedef float f32x4 __attribute__((ext_vector_type(4)));
typedef int i32x8 __attribute__((ext_vector_type(8)));
typedef float f32x16 __attribute__((ext_vector_type(16)));

#define NTOK 4096
#define CH   512

__device__ inline u16 f2bf(float f) {
  union { float f; uint32_t u; } v; v.f = f;
  uint32_t r = v.u + 0x7FFFu + ((v.u >> 16) & 1u);   // RNE
  return (u16)(r >> 16);
}
__device__ inline float bf2f(u16 b) {
  union { uint32_t u; float f; } v; v.u = (uint32_t)b << 16; return v.f;
}
__device__ inline f32x4 mfma16(s16x8 a, s16x8 b, f32x4 c) {
  return __builtin_amdgcn_mfma_f32_16x16x32_bf16(a, b, c, 0, 0, 0);
}
// block-scaled fp8 MFMA, scales = 1.0 (E8M0 bias 127) -> plain fp8 GEMM at 2x rate
__device__ inline f32x16 mfma_mx8(i32x8 a, i32x8 b, f32x16 c) {
  return __builtin_amdgcn_mfma_scale_f32_32x32x64_f8f6f4(
      a, b, c, 0 /*cbsz=fp8*/, 0 /*blgp=fp8*/,
      0, 0x7F7F7F7F, 0, 0x7F7F7F7F);
}
// pack 4 floats -> 4 fp8 e4m3 bytes (saturating)
__device__ inline uint32_t pk_fp8x4(float e0, float e1, float e2, float e3) {
#if __has_builtin(__builtin_amdgcn_cvt_pk_fp8_f32)
  int v = __builtin_amdgcn_cvt_pk_fp8_f32(e0, e1, 0, false);
  v = __builtin_amdgcn_cvt_pk_fp8_f32(e2, e3, v, true);
  return (uint32_t)v;
#else
  __hip_fp8_e4m3 a(e0), b(e1), c(e2), d(e3);
  return (uint32_t)*(u8*)&a | ((uint32_t)*(u8*)&b << 8) |
         ((uint32_t)*(u8*)&c << 16) | ((uint32_t)*(u8*)&d << 24);
#endif
}
__device__ inline u8 f2fp8(float x) {
#if __has_builtin(__builtin_amdgcn_cvt_pk_fp8_f32)
  int v = __builtin_amdgcn_cvt_pk_fp8_f32(x, x, 0, false);
  return (u8)(v & 0xFF);
#else
  __hip_fp8_e4m3 h(x); return *(u8*)&h;
#endif
}
// global -> LDS direct 16B copy (dest = wave-uniform base + lane*16)
__device__ inline void gload_lds16(const void* g, void* l) {
  __builtin_amdgcn_global_load_lds(
      (const __attribute__((address_space(1))) unsigned*)g,
      (__attribute__((address_space(3))) unsigned*)l, 16, 0, 0);
}
__device__ inline uint4 addbf8(uint4 a, uint4 b) {
  union { uint4 v; u16 h[8]; } A, B, O; A.v = a; B.v = b;
#pragma unroll
  for (int j = 0; j < 8; j++) O.h[j] = f2bf(bf2f(A.h[j]) + bf2f(B.h[j]));
  return O.v;
}
// counted-vmcnt pipeline primitives (T4): never drain to 0 mid-loop
__device__ inline void wait_vm8() {
  asm volatile("s_waitcnt vmcnt(8)" ::: "memory");
  __builtin_amdgcn_sched_barrier(0);
}
__device__ inline void wait_vm0() {
  asm volatile("s_waitcnt vmcnt(0)" ::: "memory");
  __builtin_amdgcn_sched_barrier(0);
}
__device__ inline void barrier_raw() {
  __builtin_amdgcn_sched_barrier(0);
  __builtin_amdgcn_s_barrier();
  __builtin_amdgcn_sched_barrier(0);
}

// ----------- fused prologue: GN stats (blocks 0..127) + wprep (128+) --------
__global__ __launch_bounds__(256) void prologue_kernel(
    const float* __restrict__ x, float* __restrict__ part,
    const float* w0, const float* w1, const float* w2, const float* w3,
    u16* t0, u16* t1, u16* t2, u16* t3) {
  int blk = blockIdx.x;
  int t = threadIdx.x;
  if (blk < 128) {
    // ---- GN stats: chunk c = blk&63, batch b = blk>>6 ----
    int c = blk & 63, b = blk >> 6, g = t & 31;
    const float* xb = x + (size_t)b * NTOK * CH + (size_t)c * 64 * CH + g * 16;
    float s = 0.f, q = 0.f;
    for (int p = 0; p < 8; p++) {
      const float* ptr = xb + ((size_t)p * 8 + (t >> 5)) * CH;
#pragma unroll
      for (int j = 0; j < 4; j++) {
        float4 v = *(const float4*)(ptr + j * 4);
        s += v.x + v.y + v.z + v.w;
        q += v.x * v.x + v.y * v.y + v.z * v.z + v.w * v.w;
      }
    }
    __shared__ float ls[32][8], lq[32][8];
    ls[g][t >> 5] = s; lq[g][t >> 5] = q;
    __syncthreads();
    if (t < 32) {
      float S = 0.f, Q = 0.f;
#pragma unroll
      for (int j = 0; j < 8; j++) { S += ls[t][j]; Q += lq[t][j]; }
      float2 o; o.x = S; o.y = Q;
      *(float2*)&part[(((size_t)b * 64 + c) * 32 + t) * 2] = o;
    }
  } else {
    // ---- weight prep: 1024 blocks = 4 weights x 256 (16x16) tiles ----
    int wb = blk - 128;
    int z = wb >> 8, rem = wb & 255;
    int bx = rem & 15, by = rem >> 4;
    const float* w = z == 0 ? w0 : z == 1 ? w1 : z == 2 ? w2 : w3;
    u16* wt = z == 0 ? t0 : z == 1 ? t1 : z == 2 ? t2 : t3;
    __shared__ float tile[32][33];
    int k0 = bx * 32, n0 = by * 32;
    int tx = t & 31, ty = t >> 5;
    for (int r = 0; r < 4; r++)
      tile[ty * 4 + r][tx] = w[(size_t)(k0 + ty * 4 + r) * CH + n0 + tx];
    __syncthreads();
    for (int r = 0; r < 4; r++)
      wt[(size_t)(n0 + ty * 4 + r) * CH + k0 + tx] = f2bf(tile[tx][ty * 4 + r]);
  }
}

// ------------------------- GroupNorm: apply pass ----------------------------
__global__ __launch_bounds__(256) void gn_apply_kernel(
    const float* __restrict__ x, const float* __restrict__ part,
    const float* __restrict__ gamma, const float* __restrict__ beta,
    u16* __restrict__ hn) {
  int blk = blockIdx.x, b = blk >> 9, t = threadIdx.x;
  __shared__ float msh[32], rsh[32];
  if (t < 64) {
    int g = t >> 1, half = t & 1;
    float S = 0.f, Q = 0.f;
    for (int c = half * 32; c < half * 32 + 32; c++) {
      float2 p = *(const float2*)&part[(((size_t)b * 64 + c) * 32 + g) * 2];
      S += p.x; Q += p.y;
    }
    S += __shfl_xor(S, 1, 64);
    Q += __shfl_xor(Q, 1, 64);
    if (half == 0) {
      float mean = S * (1.f / 65536.f);
      float var = Q * (1.f / 65536.f) - mean * mean;
      msh[g] = mean; rsh[g] = rsqrtf(var + 1e-5f);
    }
  }
  __syncthreads();
  size_t base = (size_t)b * NTOK * CH + (size_t)(blk & 511) * 4096 + t * 16;
  int ch0 = (t * 16) & 511;
  float mean = msh[t & 31], rstd = rsh[t & 31];
  const float* xp = x + base;
  union { u16 h[16]; uint4 v[2]; } o;
#pragma unroll
  for (int j = 0; j < 4; j++) {
    float4 xv = *(const float4*)(xp + j * 4);
    float4 gv = *(const float4*)(gamma + ch0 + j * 4);
    float4 bv = *(const float4*)(beta + ch0 + j * 4);
    o.h[j * 4 + 0] = f2bf((xv.x - mean) * rstd * gv.x + bv.x);
    o.h[j * 4 + 1] = f2bf((xv.y - mean) * rstd * gv.y + bv.y);
    o.h[j * 4 + 2] = f2bf((xv.z - mean) * rstd * gv.z + bv.z);
    o.h[j * 4 + 3] = f2bf((xv.w - mean) * rstd * gv.w + bv.w);
  }
  *(uint4*)(hn + base) = o.v[0];
  *(uint4*)(hn + base + 8) = o.v[1];
}

// ------------------------ merged q/k/v projection ---------------------------
// 128x128 tile over N=1536, BK=64, dbuf gload_lds. 4 waves (wx m-half, wy
// n-half), each 64x64 = 4x4 frags of 16x16x32 bf16.
// proj 0: qf8 (unscaled fp8), 1: kf8, 2: v -> fp8 transposed vtf8[b][c][n].
__global__ __launch_bounds__(256, 2) void qkv_gemm_kernel(
    const u16* __restrict__ A, const u16* __restrict__ Wcat,
    const float* __restrict__ bq, const float* __restrict__ bk,
    const float* __restrict__ bvv, u8* __restrict__ qf8, u8* __restrict__ kf8,
    u8* __restrict__ vtf8) {
  __shared__ __align__(16) u8 pool[65536];
  int m0 = blockIdx.x * 128, n0 = blockIdx.y * 128;
  int t = threadIdx.x, lane = t & 63, wave = t >> 6;
  int wx = wave & 1, wy = wave >> 1;
  int lane4 = lane >> 4;
  f32x4 acc[4][4] = {};                        // [mi(m)][ni(n)]
  const u16 *Asrc[4], *Bsrc[4];
  int dsto[4];
#pragma unroll
  for (int j = 0; j < 4; j++) {
    int u = t + j * 256, row = u >> 3, ch = (u & 7) ^ (row & 7);
    Asrc[j] = A + (size_t)(m0 + row) * CH + ch * 8;
    Bsrc[j] = Wcat + (size_t)(n0 + row) * CH + ch * 8;
    dsto[j] = u * 16;
  }
#pragma unroll
  for (int j = 0; j < 4; j++) {
    gload_lds16(Asrc[j], pool + dsto[j]);
    gload_lds16(Bsrc[j], pool + 32768 + dsto[j]);
  }
  __syncthreads();
  for (int kt = 0; kt < 8; kt++) {
    int co = (kt & 1) * 16384;
    const u16* Ac = (const u16*)(pool + co);
    const u16* Bc = (const u16*)(pool + 32768 + co);
    if (kt < 7) {
      int no = ((kt & 1) ^ 1) * 16384;
#pragma unroll
      for (int j = 0; j < 4; j++) {
        Asrc[j] += 64; Bsrc[j] += 64;
        gload_lds16(Asrc[j], pool + no + dsto[j]);
        gload_lds16(Bsrc[j], pool + 32768 + no + dsto[j]);
      }
    }
    __builtin_amdgcn_s_setprio(1);
#pragma unroll
    for (int ks = 0; ks < 2; ks++) {
      int kc = ks * 4 + lane4;
      s16x8 af[4], bf[4];
#pragma unroll
      for (int i = 0; i < 4; i++) {
        int ra = wx * 64 + i * 16 + (lane & 15);
        af[i] = *(const s16x8*)&Ac[ra * 64 + ((kc ^ (ra & 7)) << 3)];
        int rb = wy * 64 + i * 16 + (lane & 15);
        bf[i] = *(const s16x8*)&Bc[rb * 64 + ((kc ^ (rb & 7)) << 3)];
      }
#pragma unroll
      for (int mi = 0; mi < 4; mi++)
#pragma unroll
        for (int ni = 0; ni < 4; ni++)
          acc[mi][ni] = mfma16(af[mi], bf[ni], acc[mi][ni]);
    }
    __builtin_amdgcn_s_setprio(0);
    __syncthreads();
  }
  int proj = n0 >> 9;
  int r0l = wx * 64 + lane4 * 4;
  if (proj <= 1) {
    u8* O = proj == 0 ? qf8 : kf8;
    const float* bias = proj == 0 ? bq : bk;
#pragma unroll
    for (int mi = 0; mi < 4; mi++)
#pragma unroll
      for (int ni = 0; ni < 4; ni++) {
        int colp = (n0 & 511) + wy * 64 + ni * 16 + (lane & 15);
        float bv = bias[colp];
#pragma unroll
        for (int r = 0; r < 4; r++)
          O[(size_t)(m0 + r0l + mi * 16 + r) * CH + colp] =
              f2fp8(acc[mi][ni][r] + bv);
      }
  } else {
#pragma unroll
    for (int mi = 0; mi < 4; mi++)
#pragma unroll
      for (int ni = 0; ni < 4; ni++) {
        int colp = (n0 & 511) + wy * 64 + ni * 16 + (lane & 15);
        float bv = bvv[colp];
        int row = m0 + r0l + mi * 16;      // 4 consecutive token (n) rows
        int bb = row >> 12, nn = row & 4095;
        uint32_t p = pk_fp8x4(acc[mi][ni][0] + bv, acc[mi][ni][1] + bv,
                              acc[mi][ni][2] + bv, acc[mi][ni][3] + bv);
        *(uint32_t*)&vtf8[((size_t)bb * CH + colp) * NTOK + nn] = p;
      }
  }
}

// --------------- out projection GEMM (fuses part0+part1 add) ----------------
__global__ __launch_bounds__(256) void gemm_out_kernel(
    const u16* __restrict__ A, const u16* __restrict__ A2,
    const u16* __restrict__ Wt, const float* __restrict__ bias,
    float* __restrict__ out, const float* __restrict__ xres) {
  __shared__ __align__(16) u16 As[128 * 40];
  __shared__ __align__(16) u16 Bs[64 * 40];
  int m0 = blockIdx.x * 128, n0 = blockIdx.y * 64;
  int t = threadIdx.x, lane = t & 63, wave = t >> 6;
  int wm = wave >> 1, wn = wave & 1;
  f32x4 acc[4][2] = {};
  int arow = t >> 2, ac = t & 3;
  size_t aoff = (size_t)(m0 + arow) * CH + ac * 8;
  const u16* Bg = Wt + (size_t)(n0 + arow) * CH + ac * 8;
  uint4 a0 = addbf8(*(const uint4*)(A + aoff), *(const uint4*)(A2 + aoff));
  uint4 a1 = addbf8(*(const uint4*)(A + aoff + 64 * CH),
                    *(const uint4*)(A2 + aoff + 64 * CH));
  uint4 b0 = *(const uint4*)Bg;
  for (int kt = 0; kt < 16; kt++) {
    __syncthreads();
    *(uint4*)&As[(size_t)arow * 40 + ac * 8] = a0;
    *(uint4*)&As[(size_t)(arow + 64) * 40 + ac * 8] = a1;
    *(uint4*)&Bs[(size_t)arow * 40 + ac * 8] = b0;
    if (kt < 15) {
      aoff += 32; Bg += 32;
      a0 = addbf8(*(const uint4*)(A + aoff), *(const uint4*)(A2 + aoff));
      a1 = addbf8(*(const uint4*)(A + aoff + 64 * CH),
                  *(const uint4*)(A2 + aoff + 64 * CH));
      b0 = *(const uint4*)Bg;
    }
    __syncthreads();
    s16x8 af[4], bfr[2];
#pragma unroll
    for (int i = 0; i < 4; i++)
      af[i] = *(const s16x8*)&As[(wm * 64 + i * 16 + (lane & 15)) * 40 + (lane >> 4) * 8];
#pragma unroll
    for (int j = 0; j < 2; j++)
      bfr[j] = *(const s16x8*)&Bs[(wn * 32 + j * 16 + (lane & 15)) * 40 + (lane >> 4) * 8];
    __builtin_amdgcn_s_setprio(1);
#pragma unroll
    for (int mi = 0; mi < 4; mi++)
#pragma unroll
      for (int ni = 0; ni < 2; ni++)
        acc[mi][ni] = mfma16(af[mi], bfr[ni], acc[mi][ni]);
    __builtin_amdgcn_s_setprio(0);
  }
  int r0l = wm * 64 + ((lane >> 4) * 4);
  int c0l = wn * 32 + (lane & 15);
#pragma unroll
  for (int mi = 0; mi < 4; mi++)
#pragma unroll
    for (int ni = 0; ni < 2; ni++) {
      int col = n0 + c0l + ni * 16;
      float bv = bias[col];
#pragma unroll
      for (int r = 0; r < 4; r++) {
        size_t idx = (size_t)(m0 + r0l + mi * 16 + r) * CH + col;
        out[idx] = xres[idx] + acc[mi][ni][r] + bv;
      }
    }
}

// -- K1: S = exp(qscale*q·k^T) fp8 in/out, MX 32x32x64, counted-vmcnt pipe ---
__global__ __launch_bounds__(256, 2) void s_gemm_kernel(
    const u8* __restrict__ qf8, const u8* __restrict__ kf8,
    u8* __restrict__ S, float* __restrict__ lpart) {
  const float QS = 0.044194173824159216f;      // 1/sqrt(512)
  __shared__ __align__(16) u8 pool[65536];
  int bz = blockIdx.z;
  const u8* qb = qf8 + (size_t)bz * NTOK * CH;
  const u8* kb = kf8 + (size_t)bz * NTOK * CH;
  u8* Sg = S + (size_t)bz * NTOK * NTOK;
  float* lp = lpart + (size_t)bz * 64 * NTOK;
  int m0 = blockIdx.x * 128, n0 = blockIdx.y * 128;
  int t = threadIdx.x, lane = t & 63, wave = t >> 6;
  int wmx = wave & 1, wy = wave >> 1;          // wmx: m-half, wy: n-half
  int lh = lane >> 5;                          // k-half within fragment
  f32x16 acc[2][2] = {};                       // [ai(n-frag)][bj(m-frag)]
  const u8 *Asrc[4], *Bsrc[4];
  int dsto[4];
#pragma unroll
  for (int j = 0; j < 4; j++) {
    int u = t + j * 256, row = u >> 3, ch = (u & 7) ^ (row & 7);
    Asrc[j] = kb + (size_t)(n0 + row) * CH + ch * 16;
    Bsrc[j] = qb + (size_t)(m0 + row) * CH + ch * 16;
    dsto[j] = u * 16;
  }
  // prologue: issue tiles 0 and 1 (16 loads in flight per wave)
#pragma unroll
  for (int j = 0; j < 4; j++) {
    gload_lds16(Asrc[j], pool + dsto[j]);
    gload_lds16(Bsrc[j], pool + 32768 + dsto[j]);
  }
#pragma unroll
  for (int j = 0; j < 4; j++) {
    Asrc[j] += 128; Bsrc[j] += 128;
    gload_lds16(Asrc[j], pool + 16384 + dsto[j]);
    gload_lds16(Bsrc[j], pool + 32768 + 16384 + dsto[j]);
  }
  __builtin_amdgcn_sched_barrier(0);
#pragma unroll
  for (int kt = 0; kt < 4; kt++) {
    if (kt < 3) wait_vm8(); else wait_vm0();   // my tile-kt loads done
    barrier_raw();                             // everyone's tile-kt landed
    int co = (kt & 1) * 16384;
    const u8* Ac = pool + co;
    const u8* Bc = pool + 32768 + co;
    __builtin_amdgcn_s_setprio(1);
#pragma unroll
    for (int kh = 0; kh < 2; kh++) {           // K = 2 x 64 per 128B tile
      int cb = kh * 4 + lh * 2;
      union { i32x8 v; uint4 qq[2]; } bu[2];
#pragma unroll
      for (int bj = 0; bj < 2; bj++) {
        int rb = wmx * 64 + bj * 32 + (lane & 31);
        const u8* bp = &Bc[rb * 128];
        bu[bj].qq[0] = *(const uint4*)&bp[(cb ^ (rb & 7)) << 4];
        bu[bj].qq[1] = *(const uint4*)&bp[((cb + 1) ^ (rb & 7)) << 4];
      }
#pragma unroll
      for (int ai = 0; ai < 2; ai++) {
        int ra = wy * 64 + ai * 32 + (lane & 31);
        union { i32x8 v; uint4 qq[2]; } au;
        const u8* ap = &Ac[ra * 128];
        au.qq[0] = *(const uint4*)&ap[(cb ^ (ra & 7)) << 4];
        au.qq[1] = *(const uint4*)&ap[((cb + 1) ^ (ra & 7)) << 4];
#pragma unroll
        for (int bj = 0; bj < 2; bj++)
          acc[ai][bj] = mfma_mx8(au.v, bu[bj].v, acc[ai][bj]);
      }
    }
    __builtin_amdgcn_s_setprio(0);
    barrier_raw();                             // all waves done reading buf
    if (kt < 2) {                              // issue tile kt+2 into buf
#pragma unroll
      for (int j = 0; j < 4; j++) {
        Asrc[j] += 128; Bsrc[j] += 128;
        gload_lds16(Asrc[j], pool + co + dsto[j]);
        gload_lds16(Bsrc[j], pool + 32768 + co + dsto[j]);
      }
    }
  }
  // ---- epilogue: exp -> fp8 u32 into swizzled LDS + lpart partials ----
  uint32_t* Stile = (uint32_t*)pool;           // [128][32] words = 16 KB
  float psum[2] = {};                          // per bj (m-frag)
#pragma unroll
  for (int ai = 0; ai < 2; ai++) {
#pragma unroll
    for (int bj = 0; bj < 2; bj++) {
      int ml = wmx * 64 + bj * 32 + (lane & 31);
#pragma unroll
      for (int qd = 0; qd < 4; qd++) {
        float e0 = __expf(acc[ai][bj][qd * 4 + 0] * QS);
        float e1 = __expf(acc[ai][bj][qd * 4 + 1] * QS);
        float e2 = __expf(acc[ai][bj][qd * 4 + 2] * QS);
        float e3 = __expf(acc[ai][bj][qd * 4 + 3] * QS);
        psum[bj] += e0 + e1 + e2 + e3;
        int nw = wy * 16 + ai * 8 + qd * 2 + lh;   // u32 word (4 consec n)
        Stile[ml * 32 + (nw ^ ((ml & 7) << 2))] = pk_fp8x4(e0, e1, e2, e3);
      }
    }
  }
#pragma unroll
  for (int bj = 0; bj < 2; bj++) {
    float v = psum[bj];
    v += __shfl_xor(v, 32, 64);                // combine lh halves
    if (lane < 32) {
      int m = m0 + wmx * 64 + bj * 32 + lane;
      lp[(size_t)((n0 >> 6) + wy) * NTOK + m] = v;
    }
  }
  __syncthreads();
  // ---- coalesced store: 8 threads/row cover the full 128B row ----
#pragma unroll
  for (int p = 0; p < 4; p++) {
    int row = (t >> 3) + p * 32;
    int g = t & 7;
    int w0 = (g * 4) ^ ((row & 7) << 2);       // 16B-group swizzle (contig 4)
    uint4 v;
    v.x = Stile[row * 32 + w0 + 0];
    v.y = Stile[row * 32 + w0 + 1];
    v.z = Stile[row * 32 + w0 + 2];
    v.w = Stile[row * 32 + w0 + 3];
    *(uint4*)&Sg[(size_t)(m0 + row) * NTOK + n0 + g * 16] = v;
  }
}

// ---- K2: O_s = P_s·V / l  (MX fp8, 4 waves x 64x64, counted-vmcnt pipe) ----
__global__ __launch_bounds__(256, 2) void pv_gemm_kernel(
    const u8* __restrict__ S, const u8* __restrict__ vtf8,
    const float* __restrict__ lpart, u16* __restrict__ part0,
    u16* __restrict__ part1) {
  __shared__ __align__(16) u8 Asw[2][16384];
  __shared__ __align__(16) u8 Bsw[2][16384];
  __shared__ float linv_s[128];
  int flat = blockIdx.x + 32 * blockIdx.y + 128 * blockIdx.z;
  int xcd = flat & 7, u = flat >> 3;
  int m_t = xcd * 4 + (u & 3);
  int n_i = (u >> 2) & 3;
  int spb = u >> 4, sp = spb & 1, b = spb >> 1;
  int m0 = m_t * 128, n0 = n_i * 128, kbase = sp * 2048;
  const u8* Sb = S + (size_t)b * NTOK * NTOK;
  const u8* vb = vtf8 + (size_t)b * CH * NTOK;
  const float* lp = lpart + (size_t)b * 64 * NTOK;
  int t = threadIdx.x, lane = t & 63, wave = t >> 6;
  int wm = wave >> 1, wn = wave & 1;       // 2m x 2n waves, each 64m x 64n
  int lh = lane >> 5;
  f32x16 acc[2][2] = {};                   // [mi][ni]
  const u8 *Asrc[4], *Bsrc[4];
  int uoff[4];
#pragma unroll
  for (int j = 0; j < 4; j++) {
    int uu = t + j * 256, row = uu >> 3, ch = (uu & 7) ^ (row & 7);
    Asrc[j] = Sb + (size_t)(m0 + row) * NTOK + kbase + ch * 16;
    Bsrc[j] = vb + (size_t)(n0 + row) * NTOK + kbase + ch * 16;
    uoff[j] = uu * 16;
  }
  // prologue: issue tiles 0 and 1
#pragma unroll
  for (int j = 0; j < 4; j++) {
    gload_lds16(Asrc[j], &Asw[0][uoff[j]]);
    gload_lds16(Bsrc[j], &Bsw[0][uoff[j]]);
  }
#pragma unroll
  for (int j = 0; j < 4; j++) {
    Asrc[j] += 128; Bsrc[j] += 128;
    gload_lds16(Asrc[j], &Asw[1][uoff[j]]);
    gload_lds16(Bsrc[j], &Bsw[1][uoff[j]]);
  }
  __builtin_amdgcn_sched_barrier(0);
  for (int kt = 0; kt < 16; kt++) {
    if (kt < 15) wait_vm8(); else wait_vm0();
    barrier_raw();
    int cur = kt & 1;
    __builtin_amdgcn_s_setprio(1);
#pragma unroll
    for (int kh = 0; kh < 2; kh++) {       // K = 2 x 64 per 128B tile
      int cb = kh * 4 + lh * 2;
      union { i32x8 v; uint4 qq[2]; } bu[2];
#pragma unroll
      for (int ni = 0; ni < 2; ni++) {
        int rb = wn * 64 + ni * 32 + (lane & 31);
        const u8* bp = &Bsw[cur][rb * 128];
        bu[ni].qq[0] = *(const uint4*)&bp[(cb ^ (rb & 7)) << 4];
        bu[ni].qq[1] = *(const uint4*)&bp[((cb + 1) ^ (rb & 7)) << 4];
      }
#pragma unroll
      for (int mi = 0; mi < 2; mi++) {
        int ra = wm * 64 + mi * 32 + (lane & 31);
        union { i32x8 v; uint4 qq[2]; } au;
        const u8* ap = &Asw[cur][ra * 128];
        au.qq[0] = *(const uint4*)&ap[(cb ^ (ra & 7)) << 4];
        au.qq[1] = *(const uint4*)&ap[((cb + 1) ^ (ra & 7)) << 4];
#pragma unroll
        for (int ni = 0; ni < 2; ni++)
          acc[mi][ni] = mfma_mx8(au.v, bu[ni].v, acc[mi][ni]);
      }
    }
    __builtin_amdgcn_s_setprio(0);
    barrier_raw();
    if (kt < 14) {                         // issue tile kt+2 into buf cur
#pragma unroll
      for (int j = 0; j < 4; j++) {
        Asrc[j] += 128; Bsrc[j] += 128;
        gload_lds16(Asrc[j], &Asw[cur][uoff[j]]);
        gload_lds16(Bsrc[j], &Bsw[cur][uoff[j]]);
      }
    }
  }
  // ---- fused linv for this block's 128 rows (coalesced over lanes) ----
  if (t < 128) {
    float s = 0.f;
#pragma unroll 8
    for (int c = 0; c < 64; c++) s += lp[(size_t)c * NTOK + m0 + t];
    linv_s[t] = 1.f / s;
  }
  __syncthreads();
  u16* Od = (sp ? part1 : part0) + (size_t)b * NTOK * CH;
#pragma unroll
  for (int mi = 0; mi < 2; mi++)
#pragma unroll
    for (int ni = 0; ni < 2; ni++)
#pragma unroll
      for (int reg = 0; reg < 16; reg++) {
        int crow = (reg & 3) + 8 * (reg >> 2) + 4 * lh;
        int gr = wm * 64 + mi * 32 + crow;
        Od[(size_t)(m0 + gr) * CH + n0 + wn * 64 + ni * 32 + (lane & 31)] =
            f2bf(acc[mi][ni][reg] * linv_s[gr]);
      }
}

// ---------------------------------------------------------------------------
extern "C" void kernel_launch(void* const* d_in, const int* in_sizes, int n_in,
                              void* d_out, int out_size, void* d_ws, size_t ws_size,
                              hipStream_t stream) {
  const float* x     = (const float*)d_in[0];
  const float* gamma = (const float*)d_in[1];
  const float* beta  = (const float*)d_in[2];
  const float* wq    = (const float*)d_in[3];
  const float* bq    = (const float*)d_in[4];
  const float* wk    = (const float*)d_in[5];
  const float* bk    = (const float*)d_in[6];
  const float* wv    = (const float*)d_in[7];
  const float* bv    = (const float*)d_in[8];
  const float* wo    = (const float*)d_in[9];
  const float* bo    = (const float*)d_in[10];

  char* ws = (char*)d_ws;
  u16* hn   = (u16*)(ws + 0);                  // part0 / ao
  u16* q    = (u16*)(ws + 8388608);            // gnpart, then part1
  u8*  vtf8 = (u8*)(ws + 25165824);            // fp8 [2][512][4096] = 4 MiB
  u16* wqt  = (u16*)(ws + 33554432);           // wqt..wvt contiguous = wcat
  u16* wkt  = (u16*)(ws + 34078720);
  u16* wvt  = (u16*)(ws + 34603008);
  u16* wot  = (u16*)(ws + 35127296);
  u8*  S    = (u8*)(ws + 35651584);            // fp8 [2][4096][4096] = 32 MiB
  float* lpart = (float*)(ws + 71303168);      // [2][64][4096] f32 = 2 MiB
  u8*  qf8  = (u8*)(ws + 75497472);            // fp8 [2][4096][512] = 4 MiB
  u8*  kf8  = (u8*)(ws + 79691776);            // fp8 [2][4096][512] = 4 MiB

  float* gnpart = (float*)q;

  prologue_kernel<<<1152, 256, 0, stream>>>(x, gnpart, wq, wk, wv, wo,
                                            wqt, wkt, wvt, wot);
  gn_apply_kernel<<<1024, 256, 0, stream>>>(x, gnpart, gamma, beta, hn);
  qkv_gemm_kernel<<<dim3(64, 12), 256, 0, stream>>>(hn, wqt, bq, bk, bv, qf8, kf8, vtf8);
  s_gemm_kernel<<<dim3(32, 32, 2), 256, 0, stream>>>(qf8, kf8, S, lpart);
  pv_gemm_kernel<<<dim3(32, 4, 4), 256, 0, stream>>>(S, vtf8, lpart, hn, q);
  gemm_out_kernel<<<dim3(64, 8), 256, 0, stream>>>(hn, q, wot, bo, (float*)d_out, x);
}